// Round 19
// baseline (127.031 us; speedup 1.0000x reference)
//
#include <hip/hip_runtime.h>
#include <hip/hip_bf16.h>

// GlobalPoolDistance: RBF-kernel MMD over 3x3 patch unfolds (8,3,64,64) f32.
// N = 62*62 = 3844 patches, d = 27 (padded K=32). SIG2 = 0.2916.
// R19 = R18 with the kernel chain collapsed 4 -> 2 (isolated change).
// R18 evidence: kernel work sums to ~12us (pairs 5-8 + prep 2-3 + reduce/
// final 2) vs 39.6us wall -> launch/gap overhead of the serial 4-kernel
// chain dominates. Now: prep, then ONE pairs kernel (4 wave-jobs per
// 256-thr block, 3906 blocks) that self-reduces via the threadfence-
// reduction pattern: block thread0 writes its 4 wave partials (via LDS),
// __threadfence(), atomicAdd on a done counter (ONE atomic per block --
// 3.9k total, not the 15.6k per-wave same-line storm that cost R2/R8/R9);
// the LAST block (old==NBLK-1) reduces part[] (4 waves x 6 buckets) and
// writes out[0]. No spin -> no deadlock. Counter re-zeroed by prep every
// call (replay/poison-safe).
// R18 recap: single-MFMA gram (diag exact by construction), negligible-
// fragment skip (epilogue only when __any(g > -40): skipped values < 2^-40,
// total skipped contribution < 2e-12 vs 1e-5 threshold), 8-deep all-asm B
// prefetch + counted vmcnt (sound: every VMEM op is mine), 128x128 job per
// wave, xx/yy triangle symmetry, panel-major order, m204 XCD swizzle.
//
// ws: Am|Bm [16][3968][32] bf16 (2 x 4,063,232 B) + ctl[32] f32 (ctl[0] =
//     done counter) + part[24*1024] f32.  total ~8.3 MB.

#define NP    3844
#define NPAD  3968
#define KP    32

#define W_XY  7688     // 8 * 31 * 31  xy wave-jobs
#define W_ALL 15624    // + 2 * 8 * 496 tri wave-jobs
#define NBLK  3906     // 4 wave-jobs per block; 3906 = 8*488 + 2

static constexpr float L_F   = 4.9475824173972215f;   // log2(e)/0.2916
static constexpr float C2L_F = 9.895164834794443f;    // 2*L

using bf16x8 = __attribute__((ext_vector_type(8))) short;
using f32x4  = __attribute__((ext_vector_type(4))) float;

#define MFMA16(a, b, c) __builtin_amdgcn_mfma_f32_16x16x32_bf16((a), (b), (c), 0, 0, 0)

__device__ inline unsigned short f2bf(float f) {
    union { float f; unsigned u; } v; v.f = f;
    unsigned r = v.u + 0x7FFFu + ((v.u >> 16) & 1u);   // RNE (no NaN inputs)
    return (unsigned short)(r >> 16);
}
__device__ inline float bf2f(unsigned short h) {
    union { unsigned u; float f; } v; v.u = ((unsigned)h) << 16;
    return v.f;
}
__device__ inline void pack_store(unsigned short* dst, const unsigned short* v) {
    uint4* d = (uint4*)dst;
#pragma unroll
    for (int q = 0; q < 4; ++q) {
        unsigned w0 = (unsigned)v[8 * q + 0] | ((unsigned)v[8 * q + 1] << 16);
        unsigned w1 = (unsigned)v[8 * q + 2] | ((unsigned)v[8 * q + 3] << 16);
        unsigned w2 = (unsigned)v[8 * q + 4] | ((unsigned)v[8 * q + 5] << 16);
        unsigned w3 = (unsigned)v[8 * q + 6] | ((unsigned)v[8 * q + 7] << 16);
        d[q] = make_uint4(w0, w1, w2, w3);
    }
}

// One thread per (im, patch). A data = bf16(2L*v); B data = bf16(v);
// s' = sum over ROUNDED values; p = -s'/2 split hi/lo across column pairs.
// Block 0 thread 0 zeroes the done-counter (every call -- replay-safe).
__global__ __launch_bounds__(256) void gp_prep(const float* __restrict__ x,
                                               const float* __restrict__ y,
                                               unsigned short* __restrict__ Am,
                                               unsigned short* __restrict__ Bm,
                                               unsigned int* __restrict__ ctl) {
    if (blockIdx.x == 0 && threadIdx.x == 0) ctl[0] = 0u;
    int i = blockIdx.x * 256 + threadIdx.x;          // 16*NPAD = 63488
    if (i >= 16 * NPAD) return;
    int n = i % NPAD, im = i / NPAD;
    int b = im & 7;
    const float* src = (im >> 3) ? y : x;

    const unsigned short ONE = f2bf(1.0f);           // exact
    unsigned short hA[32], hB[32];
#pragma unroll
    for (int k = 0; k < 32; ++k) { hA[k] = 0; hB[k] = 0; }

    if (n < NP) {
        int r = n / 62, c = n % 62;
        float s = 0.0f;
#pragma unroll
        for (int ch = 0; ch < 3; ++ch)
#pragma unroll
            for (int pr = 0; pr < 3; ++pr)
#pragma unroll
                for (int pc = 0; pc < 3; ++pc) {
                    int k = ch * 9 + pr * 3 + pc;
                    float v = src[(((b * 3 + ch) * 64) + r + pr) * 64 + (c + pc)];
                    unsigned short ah = f2bf(C2L_F * v);
                    unsigned short bh = f2bf(v);
                    hA[k] = ah; hB[k] = bh;
                    s = fmaf(bf2f(ah), bf2f(bh), s);   // s' over ROUNDED values
                }
        float p = -0.5f * s;
        // A-side p: cols 27(hi)/28(lo), matched by B27=B28=1
        hA[27] = f2bf(p); hA[28] = f2bf(p - bf2f(hA[27]));
        hA[29] = ONE; hA[30] = ONE;
        // B-side p: cols 29(hi)/30(lo), matched by A29=A30=1
        hB[27] = ONE; hB[28] = ONE;
        hB[29] = f2bf(p); hB[30] = f2bf(p - bf2f(hB[29]));
    } else {
        // phantom: row/col contributes exp2(-1e30) = 0 against real AND phantom
        hA[27] = f2bf(-1e30f); hA[29] = ONE; hA[30] = ONE;
        hB[27] = ONE; hB[28] = ONE; hB[29] = f2bf(-1e30f);
    }

    pack_store(Am + (size_t)i * KP, hA);
    pack_store(Bm + (size_t)i * KP, hB);
}

// Opaque 16B global load with immediate offset: cannot be sunk or remat'd.
template<int OFF>
__device__ inline bf16x8 gload(const unsigned short* p) {
    bf16x8 r;
    asm volatile("global_load_dwordx4 %0, %1, off offset:%2"
                 : "=v"(r) : "v"(p), "i"(OFF));
    return r;
}

// 8 single-MFMA chains (128 rows x 16 cols); epilogue (32 exp2 + adds)
// SKIPPED when every g < -40 (wave-uniform test): exp2(g) < 2^-40 each,
// total skipped contribution to the output < 2e-12.
#define BODY(BHC)                                                            \
    do {                                                                     \
        const f32x4 Z = {0.f, 0.f, 0.f, 0.f};                                \
        f32x4 g0 = MFMA16(ah0, BHC, Z); f32x4 g1 = MFMA16(ah1, BHC, Z);      \
        f32x4 g2 = MFMA16(ah2, BHC, Z); f32x4 g3 = MFMA16(ah3, BHC, Z);      \
        f32x4 g4 = MFMA16(ah4, BHC, Z); f32x4 g5 = MFMA16(ah5, BHC, Z);      \
        f32x4 g6 = MFMA16(ah6, BHC, Z); f32x4 g7 = MFMA16(ah7, BHC, Z);      \
        float m0 = fmaxf(fmaxf(fmaxf(g0[0], g0[1]), g0[2]), g0[3]);          \
        float m1 = fmaxf(fmaxf(fmaxf(g1[0], g1[1]), g1[2]), g1[3]);          \
        float m2 = fmaxf(fmaxf(fmaxf(g2[0], g2[1]), g2[2]), g2[3]);          \
        float m3 = fmaxf(fmaxf(fmaxf(g3[0], g3[1]), g3[2]), g3[3]);          \
        float m4 = fmaxf(fmaxf(fmaxf(g4[0], g4[1]), g4[2]), g4[3]);          \
        float m5 = fmaxf(fmaxf(fmaxf(g5[0], g5[1]), g5[2]), g5[3]);          \
        float m6 = fmaxf(fmaxf(fmaxf(g6[0], g6[1]), g6[2]), g6[3]);          \
        float m7 = fmaxf(fmaxf(fmaxf(g7[0], g7[1]), g7[2]), g7[3]);          \
        float mm = fmaxf(fmaxf(fmaxf(fmaxf(fmaxf(fmaxf(fmaxf(m0, m1), m2),   \
                         m3), m4), m5), m6), m7);                            \
        if (__any(mm > -40.0f)) {                                            \
            s0 += __builtin_amdgcn_exp2f(g0[0]); s1 += __builtin_amdgcn_exp2f(g0[1]); \
            s2 += __builtin_amdgcn_exp2f(g0[2]); s3 += __builtin_amdgcn_exp2f(g0[3]); \
            s0 += __builtin_amdgcn_exp2f(g1[0]); s1 += __builtin_amdgcn_exp2f(g1[1]); \
            s2 += __builtin_amdgcn_exp2f(g1[2]); s3 += __builtin_amdgcn_exp2f(g1[3]); \
            s0 += __builtin_amdgcn_exp2f(g2[0]); s1 += __builtin_amdgcn_exp2f(g2[1]); \
            s2 += __builtin_amdgcn_exp2f(g2[2]); s3 += __builtin_amdgcn_exp2f(g2[3]); \
            s0 += __builtin_amdgcn_exp2f(g3[0]); s1 += __builtin_amdgcn_exp2f(g3[1]); \
            s2 += __builtin_amdgcn_exp2f(g3[2]); s3 += __builtin_amdgcn_exp2f(g3[3]); \
            s0 += __builtin_amdgcn_exp2f(g4[0]); s1 += __builtin_amdgcn_exp2f(g4[1]); \
            s2 += __builtin_amdgcn_exp2f(g4[2]); s3 += __builtin_amdgcn_exp2f(g4[3]); \
            s0 += __builtin_amdgcn_exp2f(g5[0]); s1 += __builtin_amdgcn_exp2f(g5[1]); \
            s2 += __builtin_amdgcn_exp2f(g5[2]); s3 += __builtin_amdgcn_exp2f(g5[3]); \
            s0 += __builtin_amdgcn_exp2f(g6[0]); s1 += __builtin_amdgcn_exp2f(g6[1]); \
            s2 += __builtin_amdgcn_exp2f(g6[2]); s3 += __builtin_amdgcn_exp2f(g6[3]); \
            s0 += __builtin_amdgcn_exp2f(g7[0]); s1 += __builtin_amdgcn_exp2f(g7[1]); \
            s2 += __builtin_amdgcn_exp2f(g7[2]); s3 += __builtin_amdgcn_exp2f(g7[3]); \
        }                                                                    \
    } while (0)

// step k: wait vmcnt(7-k) (b_k ready, later B loads still in flight), compute.
#define STEPN(N, CURREG)                                                     \
    do {                                                                     \
        asm volatile("s_waitcnt vmcnt(" #N ")" : "+v"(CURREG));              \
        __builtin_amdgcn_sched_barrier(0);                                   \
        BODY(CURREG);                                                        \
    } while (0)

// 4 wave-jobs per 256-thread block; self-reducing (threadfence-reduction):
// last block sums part[] and writes out. All VMEM in the job is my asm ->
// counted vmcnt sound. (256,4): 128-VGPR cap, live ~95 -> no spills.
__global__ __launch_bounds__(256, 4) void gp_pairs19(const unsigned short* __restrict__ Am,
                                                     const unsigned short* __restrict__ Bm,
                                                     float* __restrict__ part,
                                                     unsigned int* __restrict__ ctl,
                                                     float* __restrict__ out) {
    __shared__ int   sIdx[4];
    __shared__ float sVal[4];
    __shared__ int   sLast;
    __shared__ float bsum[24];

    const int phys = blockIdx.x;
    const int xcd = phys & 7, oi = phys >> 3;
    // m204 bijective swizzle: 3906 = 8*488 + 2 (q=488, r=2)
    const int blk = (xcd < 2 ? xcd * 489 : 2 * 489 + (xcd - 2) * 488) + oi;

    const int t = threadIdx.x;
    const int wv = t >> 6, l = t & 63;
    const int l15 = l & 15, lhi = l >> 4;
    const int w = blk * 4 + wv;            // wave-job id, < 15624

    int type, b, bx, by, slot;
    float wt = 1.0f;
    if (w < W_XY) {
        type = 0; b = w / 961;
        int rr = w % 961; by = rr / 31; bx = rr % 31;
        slot = rr;
    } else {
        int v = w - W_XY;
        type = 1 + v / 3968;
        int r = v % 3968; b = r / 496; int t2 = r % 496;
        by = (int)((sqrtf(8.0f * (float)t2 + 1.0f) - 1.0f) * 0.5f);
        while ((by + 1) * (by + 2) / 2 <= t2) ++by;
        while (by * (by + 1) / 2 > t2) --by;
        bx = t2 - by * (by + 1) / 2;
        wt = (bx == by) ? 1.0f : 2.0f;
        slot = t2;
    }
    int imA, imB;
    if (type == 0)      { imA = b;     imB = 8 + b; }
    else if (type == 1) { imA = b;     imB = b;     }
    else                { imA = 8 + b; imB = 8 + b; }

    // base pointers (rows 0-63 via imm offset 0..3072; rows 64-127 via +4096B)
    const size_t eA = ((size_t)(imA * NPAD + bx * 128 + l15)) * KP + lhi * 8;
    const size_t eB = ((size_t)(imB * NPAD + by * 128 + l15)) * KP + lhi * 8;
    const unsigned short* pA0 = Am + eA;
    const unsigned short* pA4 = pA0 + 2048;
    const unsigned short* pB0 = Bm + eB;
    const unsigned short* pB4 = pB0 + 2048;

    // A fragments: 8 opaque loads, pinned for the whole job (32 VGPR).
    bf16x8 ah0 = gload<0>(pA0),    ah1 = gload<1024>(pA0);
    bf16x8 ah2 = gload<2048>(pA0), ah3 = gload<3072>(pA0);
    bf16x8 ah4 = gload<0>(pA4),    ah5 = gload<1024>(pA4);
    bf16x8 ah6 = gload<2048>(pA4), ah7 = gload<3072>(pA4);

    // ALL 8 B fragments issued up front (8-deep pipeline, 32 VGPR).
    bf16x8 b0 = gload<0>(pB0),    b1 = gload<1024>(pB0);
    bf16x8 b2 = gload<2048>(pB0), b3 = gload<3072>(pB0);
    bf16x8 b4 = gload<0>(pB4),    b5 = gload<1024>(pB4);
    bf16x8 b6 = gload<2048>(pB4), b7 = gload<3072>(pB4);

    // wait A (8 oldest drain; all 8 B loads stay outstanding), pin A regs
    asm volatile("s_waitcnt vmcnt(8)"
                 : "+v"(ah0), "+v"(ah1), "+v"(ah2), "+v"(ah3),
                   "+v"(ah4), "+v"(ah5), "+v"(ah6), "+v"(ah7));
    __builtin_amdgcn_sched_barrier(0);

    float s0 = 0.f, s1 = 0.f, s2 = 0.f, s3 = 0.f;

    STEPN(7, b0);   // k=0
    STEPN(6, b1);   // k=1
    STEPN(5, b2);   // k=2
    STEPN(4, b3);   // k=3
    STEPN(3, b4);   // k=4
    STEPN(2, b5);   // k=5
    STEPN(1, b6);   // k=6
    STEPN(0, b7);   // k=7

    float sacc = wt * ((s0 + s1) + (s2 + s3));

    // wave reduce; lane0 posts (index, value) to LDS
#pragma unroll
    for (int o = 32; o > 0; o >>= 1) sacc += __shfl_down(sacc, o, 64);
    if (l == 0) { sIdx[wv] = (type * 8 + b) * 1024 + slot; sVal[wv] = sacc; }
    __syncthreads();

    // thread 0: write the block's 4 partials, release-fence, take a ticket
    if (t == 0) {
        part[sIdx[0]] = sVal[0];
        part[sIdx[1]] = sVal[1];
        part[sIdx[2]] = sVal[2];
        part[sIdx[3]] = sVal[3];
        __threadfence();                       // release: part[] visible
        unsigned old = atomicAdd(ctl, 1u);     // device-scope
        sLast = (old == (unsigned)(NBLK - 1)) ? 1 : 0;
    }
    __syncthreads();

    // last block: reduce all buckets and write the scalar output
    if (sLast) {
        __threadfence();                       // acquire: see all part[]
        // wave wv handles buckets wv, wv+4, ..., wv+20 (6 each)
        for (int bkt = wv; bkt < 24; bkt += 4) {
            const int cnt = (bkt < 8) ? 961 : 496;
            const float* p = part + bkt * 1024;
            float s = 0.0f;
            for (int i = l; i < cnt; i += 64) s += p[i];
#pragma unroll
            for (int o = 32; o > 0; o >>= 1) s += __shfl_down(s, o, 64);
            if (l == 0) bsum[bkt] = s;
        }
        __syncthreads();
        if (t == 0) {
            double s = 0.0;
            for (int b2 = 0; b2 < 8; ++b2)
                s += -2.0 * (double)bsum[b2] + (double)bsum[8 + b2]
                     + (double)bsum[16 + b2];
            out[0] = (float)(s / (8.0 * (double)NP * (double)NP));
        }
    }
}

extern "C" void kernel_launch(void* const* d_in, const int* in_sizes, int n_in,
                              void* d_out, int out_size, void* d_ws, size_t ws_size,
                              hipStream_t stream) {
    const float* x = (const float*)d_in[0];
    const float* y = (const float*)d_in[1];
    const size_t MSZ = (size_t)16 * NPAD * KP;
    unsigned short* Am = (unsigned short*)d_ws;
    unsigned short* Bm = Am + MSZ;
    unsigned int* ctl = (unsigned int*)(Bm + MSZ);   // 32 slots reserved
    float* part = (float*)ctl + 32;

    gp_prep<<<(16 * NPAD) / 256, 256, 0, stream>>>(x, y, Am, Bm, ctl);
    gp_pairs19<<<NBLK, 256, 0, stream>>>(Am, Bm, part, ctl, (float*)d_out);
}

// Round 20
// 55.097 us; speedup vs baseline: 2.3056x; 2.3056x over previous
//
#include <hip/hip_runtime.h>
#include <hip/hip_bf16.h>

// GlobalPoolDistance: RBF-kernel MMD over 3x3 patch unfolds (8,3,64,64) f32.
// N = 62*62 = 3844 patches, d = 27 (padded K=32). SIG2 = 0.2916.
// R20 = R18 (best, 39.6us) + gp_reduce/gp_final merged into ONE single-block
// gp_finish kernel (4 -> 3 launches). R19 lesson: fusing the reduction INTO
// the pairs kernel starved the hand-pinned register pipeline (VGPR 56 < ~95
// live -> scratch spills -> 122us); the allocator is function-wide, so keep
// branchy tails OUT of pinned-register kernels. The pairs kernel here is
// byte-identical to R18's.
// R18 recap: single-MFMA gram (diag exact by construction: p = -s'/2 over
// ROUNDED bf16 values, baked hi/lo across pad-col pairs), negligible-
// fragment skip (epilogue only when __any(g > -40); skipped contribution
// < 2e-12 vs 1e-5 threshold), 8-deep all-asm B prefetch + counted vmcnt
// (sound: every VMEM op is mine; live ~110 < (64,4)'s 128 cap -> no spills),
// 128x128 job per wave, xx/yy triangle symmetry, unique-slot stores (no
// atomics), panel-major order, 8x1953 bijective XCD swizzle.
//
// ws: Am|Bm [16][3968][32] bf16 (2 x 4,063,232 B) + acc[32] f32
//     + part[24*1024] f32.  total ~8.3 MB.

#define NP    3844
#define NPAD  3968
#define KP    32

#define W_XY  7688     // 8 * 31 * 31  xy wave-jobs
#define W_ALL 15624    // + 2 * 8 * 496 tri wave-jobs; 15624 = 8 * 1953
#define NBLK  15624

static constexpr float L_F   = 4.9475824173972215f;   // log2(e)/0.2916
static constexpr float C2L_F = 9.895164834794443f;    // 2*L

using bf16x8 = __attribute__((ext_vector_type(8))) short;
using f32x4  = __attribute__((ext_vector_type(4))) float;

#define MFMA16(a, b, c) __builtin_amdgcn_mfma_f32_16x16x32_bf16((a), (b), (c), 0, 0, 0)

__device__ inline unsigned short f2bf(float f) {
    union { float f; unsigned u; } v; v.f = f;
    unsigned r = v.u + 0x7FFFu + ((v.u >> 16) & 1u);   // RNE (no NaN inputs)
    return (unsigned short)(r >> 16);
}
__device__ inline float bf2f(unsigned short h) {
    union { unsigned u; float f; } v; v.u = ((unsigned)h) << 16;
    return v.f;
}
__device__ inline void pack_store(unsigned short* dst, const unsigned short* v) {
    uint4* d = (uint4*)dst;
#pragma unroll
    for (int q = 0; q < 4; ++q) {
        unsigned w0 = (unsigned)v[8 * q + 0] | ((unsigned)v[8 * q + 1] << 16);
        unsigned w1 = (unsigned)v[8 * q + 2] | ((unsigned)v[8 * q + 3] << 16);
        unsigned w2 = (unsigned)v[8 * q + 4] | ((unsigned)v[8 * q + 5] << 16);
        unsigned w3 = (unsigned)v[8 * q + 6] | ((unsigned)v[8 * q + 7] << 16);
        d[q] = make_uint4(w0, w1, w2, w3);
    }
}

// One thread per (im, patch). A data = bf16(2L*v); B data = bf16(v);
// s' = sum over ROUNDED values; p = -s'/2 split hi/lo across column pairs.
__global__ __launch_bounds__(256) void gp_prep(const float* __restrict__ x,
                                               const float* __restrict__ y,
                                               unsigned short* __restrict__ Am,
                                               unsigned short* __restrict__ Bm) {
    int i = blockIdx.x * 256 + threadIdx.x;          // 16*NPAD = 63488
    if (i >= 16 * NPAD) return;
    int n = i % NPAD, im = i / NPAD;
    int b = im & 7;
    const float* src = (im >> 3) ? y : x;

    const unsigned short ONE = f2bf(1.0f);           // exact
    unsigned short hA[32], hB[32];
#pragma unroll
    for (int k = 0; k < 32; ++k) { hA[k] = 0; hB[k] = 0; }

    if (n < NP) {
        int r = n / 62, c = n % 62;
        float s = 0.0f;
#pragma unroll
        for (int ch = 0; ch < 3; ++ch)
#pragma unroll
            for (int pr = 0; pr < 3; ++pr)
#pragma unroll
                for (int pc = 0; pc < 3; ++pc) {
                    int k = ch * 9 + pr * 3 + pc;
                    float v = src[(((b * 3 + ch) * 64) + r + pr) * 64 + (c + pc)];
                    unsigned short ah = f2bf(C2L_F * v);
                    unsigned short bh = f2bf(v);
                    hA[k] = ah; hB[k] = bh;
                    s = fmaf(bf2f(ah), bf2f(bh), s);   // s' over ROUNDED values
                }
        float p = -0.5f * s;
        // A-side p: cols 27(hi)/28(lo), matched by B27=B28=1
        hA[27] = f2bf(p); hA[28] = f2bf(p - bf2f(hA[27]));
        hA[29] = ONE; hA[30] = ONE;
        // B-side p: cols 29(hi)/30(lo), matched by A29=A30=1
        hB[27] = ONE; hB[28] = ONE;
        hB[29] = f2bf(p); hB[30] = f2bf(p - bf2f(hB[29]));
    } else {
        // phantom: row/col contributes exp2(-1e30) = 0 against real AND phantom
        hA[27] = f2bf(-1e30f); hA[29] = ONE; hA[30] = ONE;
        hB[27] = ONE; hB[28] = ONE; hB[29] = f2bf(-1e30f);
    }

    pack_store(Am + (size_t)i * KP, hA);
    pack_store(Bm + (size_t)i * KP, hB);
}

// Opaque 16B global load with immediate offset: cannot be sunk or remat'd.
template<int OFF>
__device__ inline bf16x8 gload(const unsigned short* p) {
    bf16x8 r;
    asm volatile("global_load_dwordx4 %0, %1, off offset:%2"
                 : "=v"(r) : "v"(p), "i"(OFF));
    return r;
}

// 8 single-MFMA chains (128 rows x 16 cols); epilogue (32 exp2 + adds)
// SKIPPED when every g < -40 (wave-uniform test): exp2(g) < 2^-40 each,
// total skipped contribution to the output < 2e-12.
#define BODY(BHC)                                                            \
    do {                                                                     \
        const f32x4 Z = {0.f, 0.f, 0.f, 0.f};                                \
        f32x4 g0 = MFMA16(ah0, BHC, Z); f32x4 g1 = MFMA16(ah1, BHC, Z);      \
        f32x4 g2 = MFMA16(ah2, BHC, Z); f32x4 g3 = MFMA16(ah3, BHC, Z);      \
        f32x4 g4 = MFMA16(ah4, BHC, Z); f32x4 g5 = MFMA16(ah5, BHC, Z);      \
        f32x4 g6 = MFMA16(ah6, BHC, Z); f32x4 g7 = MFMA16(ah7, BHC, Z);      \
        float m0 = fmaxf(fmaxf(fmaxf(g0[0], g0[1]), g0[2]), g0[3]);          \
        float m1 = fmaxf(fmaxf(fmaxf(g1[0], g1[1]), g1[2]), g1[3]);          \
        float m2 = fmaxf(fmaxf(fmaxf(g2[0], g2[1]), g2[2]), g2[3]);          \
        float m3 = fmaxf(fmaxf(fmaxf(g3[0], g3[1]), g3[2]), g3[3]);          \
        float m4 = fmaxf(fmaxf(fmaxf(g4[0], g4[1]), g4[2]), g4[3]);          \
        float m5 = fmaxf(fmaxf(fmaxf(g5[0], g5[1]), g5[2]), g5[3]);          \
        float m6 = fmaxf(fmaxf(fmaxf(g6[0], g6[1]), g6[2]), g6[3]);          \
        float m7 = fmaxf(fmaxf(fmaxf(g7[0], g7[1]), g7[2]), g7[3]);          \
        float mm = fmaxf(fmaxf(fmaxf(fmaxf(fmaxf(fmaxf(fmaxf(m0, m1), m2),   \
                         m3), m4), m5), m6), m7);                            \
        if (__any(mm > -40.0f)) {                                            \
            s0 += __builtin_amdgcn_exp2f(g0[0]); s1 += __builtin_amdgcn_exp2f(g0[1]); \
            s2 += __builtin_amdgcn_exp2f(g0[2]); s3 += __builtin_amdgcn_exp2f(g0[3]); \
            s0 += __builtin_amdgcn_exp2f(g1[0]); s1 += __builtin_amdgcn_exp2f(g1[1]); \
            s2 += __builtin_amdgcn_exp2f(g1[2]); s3 += __builtin_amdgcn_exp2f(g1[3]); \
            s0 += __builtin_amdgcn_exp2f(g2[0]); s1 += __builtin_amdgcn_exp2f(g2[1]); \
            s2 += __builtin_amdgcn_exp2f(g2[2]); s3 += __builtin_amdgcn_exp2f(g2[3]); \
            s0 += __builtin_amdgcn_exp2f(g3[0]); s1 += __builtin_amdgcn_exp2f(g3[1]); \
            s2 += __builtin_amdgcn_exp2f(g3[2]); s3 += __builtin_amdgcn_exp2f(g3[3]); \
            s0 += __builtin_amdgcn_exp2f(g4[0]); s1 += __builtin_amdgcn_exp2f(g4[1]); \
            s2 += __builtin_amdgcn_exp2f(g4[2]); s3 += __builtin_amdgcn_exp2f(g4[3]); \
            s0 += __builtin_amdgcn_exp2f(g5[0]); s1 += __builtin_amdgcn_exp2f(g5[1]); \
            s2 += __builtin_amdgcn_exp2f(g5[2]); s3 += __builtin_amdgcn_exp2f(g5[3]); \
            s0 += __builtin_amdgcn_exp2f(g6[0]); s1 += __builtin_amdgcn_exp2f(g6[1]); \
            s2 += __builtin_amdgcn_exp2f(g6[2]); s3 += __builtin_amdgcn_exp2f(g6[3]); \
            s0 += __builtin_amdgcn_exp2f(g7[0]); s1 += __builtin_amdgcn_exp2f(g7[1]); \
            s2 += __builtin_amdgcn_exp2f(g7[2]); s3 += __builtin_amdgcn_exp2f(g7[3]); \
        }                                                                    \
    } while (0)

// step k: wait vmcnt(7-k) (b_k ready, later B loads still in flight), compute.
#define STEPN(N, CURREG)                                                     \
    do {                                                                     \
        asm volatile("s_waitcnt vmcnt(" #N ")" : "+v"(CURREG));              \
        __builtin_amdgcn_sched_barrier(0);                                   \
        BODY(CURREG);                                                        \
    } while (0)

// One 128x128 tile per wave (64-thr block); no LDS, barriers, or atomics.
// All VMEM is inline asm -> counted vmcnt is sound. (64,4): 128-VGPR cap,
// live set ~110 -> no spills (spill VMEM would corrupt counts, R11 lesson).
__global__ __launch_bounds__(64, 4) void gp_pairs20(const unsigned short* __restrict__ Am,
                                                    const unsigned short* __restrict__ Bm,
                                                    float* __restrict__ part) {
    const int phys = blockIdx.x;
    const int w = (phys & 7) * 1953 + (phys >> 3);   // bijective, 15624 = 8*1953

    const int l = threadIdx.x & 63;
    const int l15 = l & 15, lhi = l >> 4;

    int type, b, bx, by, slot;
    float wt = 1.0f;
    if (w < W_XY) {
        type = 0; b = w / 961;
        int rr = w % 961; by = rr / 31; bx = rr % 31;
        slot = rr;
    } else {
        int v = w - W_XY;
        type = 1 + v / 3968;
        int r = v % 3968; b = r / 496; int t2 = r % 496;
        by = (int)((sqrtf(8.0f * (float)t2 + 1.0f) - 1.0f) * 0.5f);
        while ((by + 1) * (by + 2) / 2 <= t2) ++by;
        while (by * (by + 1) / 2 > t2) --by;
        bx = t2 - by * (by + 1) / 2;
        wt = (bx == by) ? 1.0f : 2.0f;
        slot = t2;
    }
    int imA, imB;
    if (type == 0)      { imA = b;     imB = 8 + b; }
    else if (type == 1) { imA = b;     imB = b;     }
    else                { imA = 8 + b; imB = 8 + b; }

    // base pointers (rows 0-63 via imm offset 0..3072; rows 64-127 via +4096B)
    const size_t eA = ((size_t)(imA * NPAD + bx * 128 + l15)) * KP + lhi * 8;
    const size_t eB = ((size_t)(imB * NPAD + by * 128 + l15)) * KP + lhi * 8;
    const unsigned short* pA0 = Am + eA;
    const unsigned short* pA4 = pA0 + 2048;
    const unsigned short* pB0 = Bm + eB;
    const unsigned short* pB4 = pB0 + 2048;

    // A fragments: 8 opaque loads, pinned for the whole job (32 VGPR).
    bf16x8 ah0 = gload<0>(pA0),    ah1 = gload<1024>(pA0);
    bf16x8 ah2 = gload<2048>(pA0), ah3 = gload<3072>(pA0);
    bf16x8 ah4 = gload<0>(pA4),    ah5 = gload<1024>(pA4);
    bf16x8 ah6 = gload<2048>(pA4), ah7 = gload<3072>(pA4);

    // ALL 8 B fragments issued up front (8-deep pipeline, 32 VGPR).
    bf16x8 b0 = gload<0>(pB0),    b1 = gload<1024>(pB0);
    bf16x8 b2 = gload<2048>(pB0), b3 = gload<3072>(pB0);
    bf16x8 b4 = gload<0>(pB4),    b5 = gload<1024>(pB4);
    bf16x8 b6 = gload<2048>(pB4), b7 = gload<3072>(pB4);

    // wait A (8 oldest drain; all 8 B loads stay outstanding), pin A regs
    asm volatile("s_waitcnt vmcnt(8)"
                 : "+v"(ah0), "+v"(ah1), "+v"(ah2), "+v"(ah3),
                   "+v"(ah4), "+v"(ah5), "+v"(ah6), "+v"(ah7));
    __builtin_amdgcn_sched_barrier(0);

    float s0 = 0.f, s1 = 0.f, s2 = 0.f, s3 = 0.f;

    STEPN(7, b0);   // k=0
    STEPN(6, b1);   // k=1
    STEPN(5, b2);   // k=2
    STEPN(4, b3);   // k=3
    STEPN(3, b4);   // k=4
    STEPN(2, b5);   // k=5
    STEPN(1, b6);   // k=6
    STEPN(0, b7);   // k=7

    float sacc = wt * ((s0 + s1) + (s2 + s3));

    // wave reduce, then ONE PLAIN STORE to a unique slot (no atomics)
#pragma unroll
    for (int o = 32; o > 0; o >>= 1) sacc += __shfl_down(sacc, o, 64);
    if (l == 0) part[(type * 8 + b) * 1024 + slot] = sacc;
}

// ONE single block: 4 waves sum the 24 buckets (6 each), combine, write out.
__global__ __launch_bounds__(256) void gp_finish(const float* __restrict__ part,
                                                 float* __restrict__ out) {
    __shared__ float bsum[24];
    const int t = threadIdx.x;
    const int wv = t >> 6, l = t & 63;

    for (int bkt = wv; bkt < 24; bkt += 4) {
        const int cnt = (bkt < 8) ? 961 : 496;
        const float* p = part + bkt * 1024;
        float s = 0.0f;
        for (int i = l; i < cnt; i += 64) s += p[i];
#pragma unroll
        for (int o = 32; o > 0; o >>= 1) s += __shfl_down(s, o, 64);
        if (l == 0) bsum[bkt] = s;
    }
    __syncthreads();
    if (t == 0) {
        double s = 0.0;
        for (int b = 0; b < 8; ++b)
            s += -2.0 * (double)bsum[b] + (double)bsum[8 + b]
                 + (double)bsum[16 + b];
        out[0] = (float)(s / (8.0 * (double)NP * (double)NP));
    }
}

extern "C" void kernel_launch(void* const* d_in, const int* in_sizes, int n_in,
                              void* d_out, int out_size, void* d_ws, size_t ws_size,
                              hipStream_t stream) {
    const float* x = (const float*)d_in[0];
    const float* y = (const float*)d_in[1];
    const size_t MSZ = (size_t)16 * NPAD * KP;
    unsigned short* Am = (unsigned short*)d_ws;
    unsigned short* Bm = Am + MSZ;
    float* part = (float*)(Bm + MSZ) + 32;

    gp_prep<<<(16 * NPAD) / 256, 256, 0, stream>>>(x, y, Am, Bm);
    gp_pairs20<<<NBLK, 64, 0, stream>>>(Am, Bm, part);
    gp_finish<<<1, 256, 0, stream>>>(part, (float*)d_out);
}

// Round 21
// 40.134 us; speedup vs baseline: 3.1652x; 1.3728x over previous
//
#include <hip/hip_runtime.h>
#include <hip/hip_bf16.h>

// GlobalPoolDistance: RBF-kernel MMD over 3x3 patch unfolds (8,3,64,64) f32.
// N = 62*62 = 3844 patches, d = 27 (padded K=32). SIG2 = 0.2916.
// R21 = R18 pairs (byte-identical pipeline) + weight-folded DENSE partials +
// wide parallel finish. R20 post-mortem: fusing reduce+final into ONE 4-wave
// block serialized ~96KB of latency-bound reads (+15us) -- Guideline-1
// violation. Fix: (1) fold combine weights into the pairs store (wt = -2 xy,
// +1 sym-diag, +2 sym-offdiag) so the answer is just sum(part)/(8N^2);
// (2) dense part[w] (15624 contiguous f32, all valid -> poison-safe);
// (3) gp_finish = 1 block x 1024 thr (16 waves), coalesced grid-stride sum.
// R18 recap: single-MFMA gram (diag exact by construction: p = -s'/2 over
// ROUNDED bf16 values, baked hi/lo across pad-col pairs), negligible-
// fragment skip (epilogue only when __any(g > -40); skipped contribution
// < 2e-12 vs 1e-5 threshold), 8-deep all-asm B prefetch + counted vmcnt
// (sound: every VMEM op is mine; live ~110 < (64,4)'s 128 cap -> no
// spills), 128x128 job per wave, xx/yy triangle symmetry, panel-major
// order, 8x1953 bijective XCD swizzle.
//
// ws: Am|Bm [16][3968][32] bf16 (2 x 4,063,232 B) + part[15624] f32.

#define NP    3844
#define NPAD  3968
#define KP    32

#define W_XY  7688     // 8 * 31 * 31  xy wave-jobs
#define W_ALL 15624    // + 2 * 8 * 496 tri wave-jobs; 15624 = 8 * 1953
#define NBLK  15624

static constexpr float L_F   = 4.9475824173972215f;   // log2(e)/0.2916
static constexpr float C2L_F = 9.895164834794443f;    // 2*L

using bf16x8 = __attribute__((ext_vector_type(8))) short;
using f32x4  = __attribute__((ext_vector_type(4))) float;

#define MFMA16(a, b, c) __builtin_amdgcn_mfma_f32_16x16x32_bf16((a), (b), (c), 0, 0, 0)

__device__ inline unsigned short f2bf(float f) {
    union { float f; unsigned u; } v; v.f = f;
    unsigned r = v.u + 0x7FFFu + ((v.u >> 16) & 1u);   // RNE (no NaN inputs)
    return (unsigned short)(r >> 16);
}
__device__ inline float bf2f(unsigned short h) {
    union { unsigned u; float f; } v; v.u = ((unsigned)h) << 16;
    return v.f;
}
__device__ inline void pack_store(unsigned short* dst, const unsigned short* v) {
    uint4* d = (uint4*)dst;
#pragma unroll
    for (int q = 0; q < 4; ++q) {
        unsigned w0 = (unsigned)v[8 * q + 0] | ((unsigned)v[8 * q + 1] << 16);
        unsigned w1 = (unsigned)v[8 * q + 2] | ((unsigned)v[8 * q + 3] << 16);
        unsigned w2 = (unsigned)v[8 * q + 4] | ((unsigned)v[8 * q + 5] << 16);
        unsigned w3 = (unsigned)v[8 * q + 6] | ((unsigned)v[8 * q + 7] << 16);
        d[q] = make_uint4(w0, w1, w2, w3);
    }
}

// One thread per (im, patch). A data = bf16(2L*v); B data = bf16(v);
// s' = sum over ROUNDED values; p = -s'/2 split hi/lo across column pairs.
__global__ __launch_bounds__(256) void gp_prep(const float* __restrict__ x,
                                               const float* __restrict__ y,
                                               unsigned short* __restrict__ Am,
                                               unsigned short* __restrict__ Bm) {
    int i = blockIdx.x * 256 + threadIdx.x;          // 16*NPAD = 63488
    if (i >= 16 * NPAD) return;
    int n = i % NPAD, im = i / NPAD;
    int b = im & 7;
    const float* src = (im >> 3) ? y : x;

    const unsigned short ONE = f2bf(1.0f);           // exact
    unsigned short hA[32], hB[32];
#pragma unroll
    for (int k = 0; k < 32; ++k) { hA[k] = 0; hB[k] = 0; }

    if (n < NP) {
        int r = n / 62, c = n % 62;
        float s = 0.0f;
#pragma unroll
        for (int ch = 0; ch < 3; ++ch)
#pragma unroll
            for (int pr = 0; pr < 3; ++pr)
#pragma unroll
                for (int pc = 0; pc < 3; ++pc) {
                    int k = ch * 9 + pr * 3 + pc;
                    float v = src[(((b * 3 + ch) * 64) + r + pr) * 64 + (c + pc)];
                    unsigned short ah = f2bf(C2L_F * v);
                    unsigned short bh = f2bf(v);
                    hA[k] = ah; hB[k] = bh;
                    s = fmaf(bf2f(ah), bf2f(bh), s);   // s' over ROUNDED values
                }
        float p = -0.5f * s;
        // A-side p: cols 27(hi)/28(lo), matched by B27=B28=1
        hA[27] = f2bf(p); hA[28] = f2bf(p - bf2f(hA[27]));
        hA[29] = ONE; hA[30] = ONE;
        // B-side p: cols 29(hi)/30(lo), matched by A29=A30=1
        hB[27] = ONE; hB[28] = ONE;
        hB[29] = f2bf(p); hB[30] = f2bf(p - bf2f(hB[29]));
    } else {
        // phantom: row/col contributes exp2(-1e30) = 0 against real AND phantom
        hA[27] = f2bf(-1e30f); hA[29] = ONE; hA[30] = ONE;
        hB[27] = ONE; hB[28] = ONE; hB[29] = f2bf(-1e30f);
    }

    pack_store(Am + (size_t)i * KP, hA);
    pack_store(Bm + (size_t)i * KP, hB);
}

// Opaque 16B global load with immediate offset: cannot be sunk or remat'd.
template<int OFF>
__device__ inline bf16x8 gload(const unsigned short* p) {
    bf16x8 r;
    asm volatile("global_load_dwordx4 %0, %1, off offset:%2"
                 : "=v"(r) : "v"(p), "i"(OFF));
    return r;
}

// 8 single-MFMA chains (128 rows x 16 cols); epilogue (32 exp2 + adds)
// SKIPPED when every g < -40 (wave-uniform test): exp2(g) < 2^-40 each,
// total skipped contribution to the output < 2e-12.
#define BODY(BHC)                                                            \
    do {                                                                     \
        const f32x4 Z = {0.f, 0.f, 0.f, 0.f};                                \
        f32x4 g0 = MFMA16(ah0, BHC, Z); f32x4 g1 = MFMA16(ah1, BHC, Z);      \
        f32x4 g2 = MFMA16(ah2, BHC, Z); f32x4 g3 = MFMA16(ah3, BHC, Z);      \
        f32x4 g4 = MFMA16(ah4, BHC, Z); f32x4 g5 = MFMA16(ah5, BHC, Z);      \
        f32x4 g6 = MFMA16(ah6, BHC, Z); f32x4 g7 = MFMA16(ah7, BHC, Z);      \
        float m0 = fmaxf(fmaxf(fmaxf(g0[0], g0[1]), g0[2]), g0[3]);          \
        float m1 = fmaxf(fmaxf(fmaxf(g1[0], g1[1]), g1[2]), g1[3]);          \
        float m2 = fmaxf(fmaxf(fmaxf(g2[0], g2[1]), g2[2]), g2[3]);          \
        float m3 = fmaxf(fmaxf(fmaxf(g3[0], g3[1]), g3[2]), g3[3]);          \
        float m4 = fmaxf(fmaxf(fmaxf(g4[0], g4[1]), g4[2]), g4[3]);          \
        float m5 = fmaxf(fmaxf(fmaxf(g5[0], g5[1]), g5[2]), g5[3]);          \
        float m6 = fmaxf(fmaxf(fmaxf(g6[0], g6[1]), g6[2]), g6[3]);          \
        float m7 = fmaxf(fmaxf(fmaxf(g7[0], g7[1]), g7[2]), g7[3]);          \
        float mm = fmaxf(fmaxf(fmaxf(fmaxf(fmaxf(fmaxf(fmaxf(m0, m1), m2),   \
                         m3), m4), m5), m6), m7);                            \
        if (__any(mm > -40.0f)) {                                            \
            s0 += __builtin_amdgcn_exp2f(g0[0]); s1 += __builtin_amdgcn_exp2f(g0[1]); \
            s2 += __builtin_amdgcn_exp2f(g0[2]); s3 += __builtin_amdgcn_exp2f(g0[3]); \
            s0 += __builtin_amdgcn_exp2f(g1[0]); s1 += __builtin_amdgcn_exp2f(g1[1]); \
            s2 += __builtin_amdgcn_exp2f(g1[2]); s3 += __builtin_amdgcn_exp2f(g1[3]); \
            s0 += __builtin_amdgcn_exp2f(g2[0]); s1 += __builtin_amdgcn_exp2f(g2[1]); \
            s2 += __builtin_amdgcn_exp2f(g2[2]); s3 += __builtin_amdgcn_exp2f(g2[3]); \
            s0 += __builtin_amdgcn_exp2f(g3[0]); s1 += __builtin_amdgcn_exp2f(g3[1]); \
            s2 += __builtin_amdgcn_exp2f(g3[2]); s3 += __builtin_amdgcn_exp2f(g3[3]); \
            s0 += __builtin_amdgcn_exp2f(g4[0]); s1 += __builtin_amdgcn_exp2f(g4[1]); \
            s2 += __builtin_amdgcn_exp2f(g4[2]); s3 += __builtin_amdgcn_exp2f(g4[3]); \
            s0 += __builtin_amdgcn_exp2f(g5[0]); s1 += __builtin_amdgcn_exp2f(g5[1]); \
            s2 += __builtin_amdgcn_exp2f(g5[2]); s3 += __builtin_amdgcn_exp2f(g5[3]); \
            s0 += __builtin_amdgcn_exp2f(g6[0]); s1 += __builtin_amdgcn_exp2f(g6[1]); \
            s2 += __builtin_amdgcn_exp2f(g6[2]); s3 += __builtin_amdgcn_exp2f(g6[3]); \
            s0 += __builtin_amdgcn_exp2f(g7[0]); s1 += __builtin_amdgcn_exp2f(g7[1]); \
            s2 += __builtin_amdgcn_exp2f(g7[2]); s3 += __builtin_amdgcn_exp2f(g7[3]); \
        }                                                                    \
    } while (0)

// step k: wait vmcnt(7-k) (b_k ready, later B loads still in flight), compute.
#define STEPN(N, CURREG)                                                     \
    do {                                                                     \
        asm volatile("s_waitcnt vmcnt(" #N ")" : "+v"(CURREG));              \
        __builtin_amdgcn_sched_barrier(0);                                   \
        BODY(CURREG);                                                        \
    } while (0)

// One 128x128 tile per wave (64-thr block); no LDS, barriers, or atomics.
// All VMEM is inline asm -> counted vmcnt is sound. (64,4): 128-VGPR cap,
// live set ~110 -> no spills (spill VMEM would corrupt counts, R11 lesson).
// Combine weight folded into the store: wt = -2 (xy), +1 (sym diag),
// +2 (sym off-diag); dense part[w].
__global__ __launch_bounds__(64, 4) void gp_pairs21(const unsigned short* __restrict__ Am,
                                                    const unsigned short* __restrict__ Bm,
                                                    float* __restrict__ part) {
    const int phys = blockIdx.x;
    const int w = (phys & 7) * 1953 + (phys >> 3);   // bijective, 15624 = 8*1953

    const int l = threadIdx.x & 63;
    const int l15 = l & 15, lhi = l >> 4;

    int type, b, bx, by;
    float wt;
    if (w < W_XY) {
        type = 0; b = w / 961;
        int rr = w % 961; by = rr / 31; bx = rr % 31;
        wt = -2.0f;
    } else {
        int v = w - W_XY;
        type = 1 + v / 3968;
        int r = v % 3968; b = r / 496; int t2 = r % 496;
        by = (int)((sqrtf(8.0f * (float)t2 + 1.0f) - 1.0f) * 0.5f);
        while ((by + 1) * (by + 2) / 2 <= t2) ++by;
        while (by * (by + 1) / 2 > t2) --by;
        bx = t2 - by * (by + 1) / 2;
        wt = (bx == by) ? 1.0f : 2.0f;
    }
    int imA, imB;
    if (type == 0)      { imA = b;     imB = 8 + b; }
    else if (type == 1) { imA = b;     imB = b;     }
    else                { imA = 8 + b; imB = 8 + b; }

    // base pointers (rows 0-63 via imm offset 0..3072; rows 64-127 via +4096B)
    const size_t eA = ((size_t)(imA * NPAD + bx * 128 + l15)) * KP + lhi * 8;
    const size_t eB = ((size_t)(imB * NPAD + by * 128 + l15)) * KP + lhi * 8;
    const unsigned short* pA0 = Am + eA;
    const unsigned short* pA4 = pA0 + 2048;
    const unsigned short* pB0 = Bm + eB;
    const unsigned short* pB4 = pB0 + 2048;

    // A fragments: 8 opaque loads, pinned for the whole job (32 VGPR).
    bf16x8 ah0 = gload<0>(pA0),    ah1 = gload<1024>(pA0);
    bf16x8 ah2 = gload<2048>(pA0), ah3 = gload<3072>(pA0);
    bf16x8 ah4 = gload<0>(pA4),    ah5 = gload<1024>(pA4);
    bf16x8 ah6 = gload<2048>(pA4), ah7 = gload<3072>(pA4);

    // ALL 8 B fragments issued up front (8-deep pipeline, 32 VGPR).
    bf16x8 b0 = gload<0>(pB0),    b1 = gload<1024>(pB0);
    bf16x8 b2 = gload<2048>(pB0), b3 = gload<3072>(pB0);
    bf16x8 b4 = gload<0>(pB4),    b5 = gload<1024>(pB4);
    bf16x8 b6 = gload<2048>(pB4), b7 = gload<3072>(pB4);

    // wait A (8 oldest drain; all 8 B loads stay outstanding), pin A regs
    asm volatile("s_waitcnt vmcnt(8)"
                 : "+v"(ah0), "+v"(ah1), "+v"(ah2), "+v"(ah3),
                   "+v"(ah4), "+v"(ah5), "+v"(ah6), "+v"(ah7));
    __builtin_amdgcn_sched_barrier(0);

    float s0 = 0.f, s1 = 0.f, s2 = 0.f, s3 = 0.f;

    STEPN(7, b0);   // k=0
    STEPN(6, b1);   // k=1
    STEPN(5, b2);   // k=2
    STEPN(4, b3);   // k=3
    STEPN(3, b4);   // k=4
    STEPN(2, b5);   // k=5
    STEPN(1, b6);   // k=6
    STEPN(0, b7);   // k=7

    float sacc = wt * ((s0 + s1) + (s2 + s3));

    // wave reduce, then ONE PLAIN STORE to the dense slot (no atomics)
#pragma unroll
    for (int o = 32; o > 0; o >>= 1) sacc += __shfl_down(sacc, o, 64);
    if (l == 0) part[w] = sacc;
}

// ONE block x 1024 threads (16 waves): coalesced grid-stride sum of the
// dense weighted partials; answer = sum / (8 N^2).
__global__ __launch_bounds__(1024) void gp_finish(const float* __restrict__ part,
                                                  float* __restrict__ out) {
    __shared__ float red[16];
    const int t = threadIdx.x;
    const int wv = t >> 6, l = t & 63;

    float s = 0.0f;
    for (int i = t; i < W_ALL; i += 1024) s += part[i];
#pragma unroll
    for (int o = 32; o > 0; o >>= 1) s += __shfl_down(s, o, 64);
    if (l == 0) red[wv] = s;
    __syncthreads();
    if (t == 0) {
        double d = 0.0;
#pragma unroll
        for (int i = 0; i < 16; ++i) d += (double)red[i];
        out[0] = (float)(d / (8.0 * (double)NP * (double)NP));
    }
}

extern "C" void kernel_launch(void* const* d_in, const int* in_sizes, int n_in,
                              void* d_out, int out_size, void* d_ws, size_t ws_size,
                              hipStream_t stream) {
    const float* x = (const float*)d_in[0];
    const float* y = (const float*)d_in[1];
    const size_t MSZ = (size_t)16 * NPAD * KP;
    unsigned short* Am = (unsigned short*)d_ws;
    unsigned short* Bm = Am + MSZ;
    float* part = (float*)(Bm + MSZ);

    gp_prep<<<(16 * NPAD) / 256, 256, 0, stream>>>(x, y, Am, Bm);
    gp_pairs21<<<NBLK, 64, 0, stream>>>(Am, Bm, part);
    gp_finish<<<1, 1024, 0, stream>>>(part, (float*)d_out);
}

// Round 22
// 37.069 us; speedup vs baseline: 3.4269x; 1.0827x over previous
//
#include <hip/hip_runtime.h>
#include <hip/hip_bf16.h>

// GlobalPoolDistance: RBF-kernel MMD over 3x3 patch unfolds (8,3,64,64) f32.
// N = 62*62 = 3844 patches, d = 27 (padded K=32). SIG2 = 0.2916.
// R22 = R16's B-sharing structure x R17/R18's math. R21 evidence: launch
// merge (4->3) bought 0 -> wall is pairs' L2 traffic (1 B/pair = 244 MB at
// ~10 TB/s ~ 24us). This round: 256x256 tile per 4-wave block (NPAD=4096),
// B panel (16KB, single matrix) staged ONCE into LDS and shared by 4 waves;
// A = 4 frags/wave in registers. 0.5 B/pair -> 122 MB -> ~12us.
// Sync is correctness-robust: NO manual vmcnt anywhere. A = plain loads +
// empty-asm keep-alive tie (R14-proven against sinking/remat); B staging =
// global_load_lds builtin (compiler-visible); __syncthreads' vmcnt(0) drain
// covers both (R16-proven). Live ~60 VGPR < (256,4)'s 128 cap -> no spills.
// R17/R18 math recap: single-MFMA gram (diag exact by construction: p =
// -s'/2 over ROUNDED bf16 values, baked hi/lo across pad-col pairs);
// negligible-fragment skip (epilogue only when __any(g > -40); skipped
// contribution < 2e-12 vs 1e-5 threshold); weights folded into the store
// (xy=-2, sym diag=+1, off-diag=+2) -> answer = sum(part)/(8N^2).
//
// ws: Am|Bm [16][4096][32] bf16 (2 x 4,194,304 B) + part[4224] f32.

#define NP    3844
#define NPAD  4096
#define KP    32

#define XYB   2048     // 8 * 16 * 16 xy tile-blocks
#define NBLK  4224     // + 2 * 8 * 136 tri tile-blocks = 8 * 528

static constexpr float L_F   = 4.9475824173972215f;   // log2(e)/0.2916
static constexpr float C2L_F = 9.895164834794443f;    // 2*L

using bf16x8 = __attribute__((ext_vector_type(8))) short;
using f32x4  = __attribute__((ext_vector_type(4))) float;

#define MFMA16(a, b, c) __builtin_amdgcn_mfma_f32_16x16x32_bf16((a), (b), (c), 0, 0, 0)

__device__ inline unsigned short f2bf(float f) {
    union { float f; unsigned u; } v; v.f = f;
    unsigned r = v.u + 0x7FFFu + ((v.u >> 16) & 1u);   // RNE (no NaN inputs)
    return (unsigned short)(r >> 16);
}
__device__ inline float bf2f(unsigned short h) {
    union { unsigned u; float f; } v; v.u = ((unsigned)h) << 16;
    return v.f;
}
__device__ inline void pack_store(unsigned short* dst, const unsigned short* v) {
    uint4* d = (uint4*)dst;
#pragma unroll
    for (int q = 0; q < 4; ++q) {
        unsigned w0 = (unsigned)v[8 * q + 0] | ((unsigned)v[8 * q + 1] << 16);
        unsigned w1 = (unsigned)v[8 * q + 2] | ((unsigned)v[8 * q + 3] << 16);
        unsigned w2 = (unsigned)v[8 * q + 4] | ((unsigned)v[8 * q + 5] << 16);
        unsigned w3 = (unsigned)v[8 * q + 6] | ((unsigned)v[8 * q + 7] << 16);
        d[q] = make_uint4(w0, w1, w2, w3);
    }
}

// One thread per (im, patch). A data = bf16(2L*v); B data = bf16(v);
// s' = sum over ROUNDED values; p = -s'/2 split hi/lo across column pairs.
__global__ __launch_bounds__(256) void gp_prep(const float* __restrict__ x,
                                               const float* __restrict__ y,
                                               unsigned short* __restrict__ Am,
                                               unsigned short* __restrict__ Bm) {
    int i = blockIdx.x * 256 + threadIdx.x;          // 16*NPAD = 65536
    if (i >= 16 * NPAD) return;
    int n = i % NPAD, im = i / NPAD;
    int b = im & 7;
    const float* src = (im >> 3) ? y : x;

    const unsigned short ONE = f2bf(1.0f);           // exact
    unsigned short hA[32], hB[32];
#pragma unroll
    for (int k = 0; k < 32; ++k) { hA[k] = 0; hB[k] = 0; }

    if (n < NP) {
        int r = n / 62, c = n % 62;
        float s = 0.0f;
#pragma unroll
        for (int ch = 0; ch < 3; ++ch)
#pragma unroll
            for (int pr = 0; pr < 3; ++pr)
#pragma unroll
                for (int pc = 0; pc < 3; ++pc) {
                    int k = ch * 9 + pr * 3 + pc;
                    float v = src[(((b * 3 + ch) * 64) + r + pr) * 64 + (c + pc)];
                    unsigned short ah = f2bf(C2L_F * v);
                    unsigned short bh = f2bf(v);
                    hA[k] = ah; hB[k] = bh;
                    s = fmaf(bf2f(ah), bf2f(bh), s);   // s' over ROUNDED values
                }
        float p = -0.5f * s;
        // A-side p: cols 27(hi)/28(lo), matched by B27=B28=1
        hA[27] = f2bf(p); hA[28] = f2bf(p - bf2f(hA[27]));
        hA[29] = ONE; hA[30] = ONE;
        // B-side p: cols 29(hi)/30(lo), matched by A29=A30=1
        hB[27] = ONE; hB[28] = ONE;
        hB[29] = f2bf(p); hB[30] = f2bf(p - bf2f(hB[29]));
    } else {
        // phantom: row/col contributes exp2(-1e30) = 0 against real AND phantom
        hA[27] = f2bf(-1e30f); hA[29] = ONE; hA[30] = ONE;
        hB[27] = ONE; hB[28] = ONE; hB[29] = f2bf(-1e30f);
    }

    pack_store(Am + (size_t)i * KP, hA);
    pack_store(Bm + (size_t)i * KP, hB);
}

// global -> LDS direct (1KB per call: 64 lanes x 16B), compiler-visible.
__device__ inline void glds(const unsigned short* p, char* lptr) {
    __builtin_amdgcn_global_load_lds(
        (const __attribute__((address_space(1))) void*)p,
        (__attribute__((address_space(3))) void*)lptr, 16, 0, 0);
}

// 4 single-MFMA chains (64 rows x 16 cols); epilogue (16 exp2 + adds)
// SKIPPED when every g < -40 (wave-uniform test): exp2(g) < 2^-40 each,
// total skipped contribution to the output < 2e-12.
#define BODY4(BHC)                                                           \
    do {                                                                     \
        const f32x4 Z = {0.f, 0.f, 0.f, 0.f};                                \
        f32x4 g0 = MFMA16(ah0, BHC, Z); f32x4 g1 = MFMA16(ah1, BHC, Z);      \
        f32x4 g2 = MFMA16(ah2, BHC, Z); f32x4 g3 = MFMA16(ah3, BHC, Z);      \
        float m0 = fmaxf(fmaxf(fmaxf(g0[0], g0[1]), g0[2]), g0[3]);          \
        float m1 = fmaxf(fmaxf(fmaxf(g1[0], g1[1]), g1[2]), g1[3]);          \
        float m2 = fmaxf(fmaxf(fmaxf(g2[0], g2[1]), g2[2]), g2[3]);          \
        float m3 = fmaxf(fmaxf(fmaxf(g3[0], g3[1]), g3[2]), g3[3]);          \
        float mm = fmaxf(fmaxf(fmaxf(m0, m1), m2), m3);                      \
        if (__any(mm > -40.0f)) {                                            \
            s0 += __builtin_amdgcn_exp2f(g0[0]); s1 += __builtin_amdgcn_exp2f(g0[1]); \
            s2 += __builtin_amdgcn_exp2f(g0[2]); s3 += __builtin_amdgcn_exp2f(g0[3]); \
            s0 += __builtin_amdgcn_exp2f(g1[0]); s1 += __builtin_amdgcn_exp2f(g1[1]); \
            s2 += __builtin_amdgcn_exp2f(g1[2]); s3 += __builtin_amdgcn_exp2f(g1[3]); \
            s0 += __builtin_amdgcn_exp2f(g2[0]); s1 += __builtin_amdgcn_exp2f(g2[1]); \
            s2 += __builtin_amdgcn_exp2f(g2[2]); s3 += __builtin_amdgcn_exp2f(g2[3]); \
            s0 += __builtin_amdgcn_exp2f(g3[0]); s1 += __builtin_amdgcn_exp2f(g3[1]); \
            s2 += __builtin_amdgcn_exp2f(g3[2]); s3 += __builtin_amdgcn_exp2f(g3[3]); \
        }                                                                    \
    } while (0)

// 256x256 tile per 4-wave block. B panel (single matrix, 16KB) in LDS
// shared by all 4 waves; wave wv owns rows [si*256 + wv*64, +64).
// No manual waitcnt: __syncthreads' vmcnt(0) drain covers A plain loads
// (kept live by the empty-asm tie) and the B staging DMA.
__global__ __launch_bounds__(256, 4) void gp_pairs22(const unsigned short* __restrict__ Am,
                                                     const unsigned short* __restrict__ Bm,
                                                     float* __restrict__ part) {
    __shared__ __align__(16) char ldsB[16384];
    __shared__ float red[4];

    const int phys = blockIdx.x;
    const int blk = (phys & 7) * 528 + (phys >> 3);   // bijective, 4224 = 8*528

    const int t = threadIdx.x;
    const int wv = t >> 6, l = t & 63;
    const int l15 = l & 15, lhi = l >> 4;

    int type, b, si, sj;
    float wt;
    if (blk < XYB) {
        type = 0; b = blk >> 8;
        int rr = blk & 255; si = rr >> 4; sj = rr & 15;
        wt = -2.0f;
    } else {
        int id2 = blk - XYB;
        type = 1 + id2 / 1088;
        int r = id2 % 1088; b = r / 136; int t2 = r % 136;
        sj = (int)((sqrtf(8.0f * (float)t2 + 1.0f) - 1.0f) * 0.5f);
        while ((sj + 1) * (sj + 2) / 2 <= t2) ++sj;
        while (sj * (sj + 1) / 2 > t2) --sj;
        si = t2 - sj * (sj + 1) / 2;                  // si <= sj
        wt = (si == sj) ? 1.0f : 2.0f;
    }
    int imA, imB;
    if (type == 0)      { imA = b;     imB = 8 + b; }
    else if (type == 1) { imA = b;     imB = b;     }
    else                { imA = 8 + b; imB = 8 + b; }

    // A fragments: 64 rows for this wave (4 frags, 16 VGPR), plain loads +
    // keep-alive tie (cannot be sunk/remat'd; syncthreads drains the loads).
    const size_t eA = ((size_t)(imA * NPAD + si * 256 + wv * 64 + l15)) * KP + lhi * 8;
    const unsigned short* pA = Am + eA;
    bf16x8 ah0 = *(const bf16x8*)(pA);
    bf16x8 ah1 = *(const bf16x8*)(pA + 512);
    bf16x8 ah2 = *(const bf16x8*)(pA + 1024);
    bf16x8 ah3 = *(const bf16x8*)(pA + 1536);
    asm volatile("" : "+v"(ah0), "+v"(ah1), "+v"(ah2), "+v"(ah3));

    // Stage the 256-col B panel (16KB) cooperatively: 16 chunks of 1KB;
    // wave wv stages chunks wv*4..wv*4+3 (wave-uniform LDS dst, per-lane src).
#pragma unroll
    for (int j = 0; j < 4; ++j) {
        const int q = wv * 4 + j;
        const unsigned short* src = Bm
            + ((size_t)(imB * NPAD + sj * 256 + q * 16 + l15)) * KP + lhi * 8;
        glds(src, ldsB + q * 1024);
    }
    __syncthreads();   // vmcnt(0)+lgkmcnt(0) drain (A loads + staging) + barrier

    float s0 = 0.f, s1 = 0.f, s2 = 0.f, s3 = 0.f;

    // 16 barrier-free cg steps: B frag from LDS (conflict-free lane*16B),
    // 4 MFMA + skip-guarded 16 exp2 each.
#pragma unroll
    for (int cg = 0; cg < 16; ++cg) {
        const bf16x8 bhc = *(const bf16x8*)(ldsB + cg * 1024 + l * 16);
        BODY4(bhc);
    }

    float sacc = (s0 + s1) + (s2 + s3);

    // wave reduce; cross-wave combine; one plain store per block (no atomics)
#pragma unroll
    for (int o = 32; o > 0; o >>= 1) sacc += __shfl_down(sacc, o, 64);
    if (l == 0) red[wv] = sacc;
    __syncthreads();
    if (t == 0) part[blk] = wt * ((red[0] + red[1]) + (red[2] + red[3]));
}

// ONE block x 1024 threads (16 waves): coalesced sum of the 4224 weighted
// block partials; answer = sum / (8 N^2).
__global__ __launch_bounds__(1024) void gp_finish(const float* __restrict__ part,
                                                  float* __restrict__ out) {
    __shared__ float red[16];
    const int t = threadIdx.x;
    const int wv = t >> 6, l = t & 63;

    float s = 0.0f;
    for (int i = t; i < NBLK; i += 1024) s += part[i];
#pragma unroll
    for (int o = 32; o > 0; o >>= 1) s += __shfl_down(s, o, 64);
    if (l == 0) red[wv] = s;
    __syncthreads();
    if (t == 0) {
        double d = 0.0;
#pragma unroll
        for (int i = 0; i < 16; ++i) d += (double)red[i];
        out[0] = (float)(d / (8.0 * (double)NP * (double)NP));
    }
}

extern "C" void kernel_launch(void* const* d_in, const int* in_sizes, int n_in,
                              void* d_out, int out_size, void* d_ws, size_t ws_size,
                              hipStream_t stream) {
    const float* x = (const float*)d_in[0];
    const float* y = (const float*)d_in[1];
    const size_t MSZ = (size_t)16 * NPAD * KP;
    unsigned short* Am = (unsigned short*)d_ws;
    unsigned short* Bm = Am + MSZ;
    float* part = (float*)(Bm + MSZ);

    gp_prep<<<(16 * NPAD) / 256, 256, 0, stream>>>(x, y, Am, Bm);
    gp_pairs22<<<NBLK, 256, 0, stream>>>(Am, Bm, part);
    gp_finish<<<1, 1024, 0, stream>>>(part, (float*)d_out);
}